// Round 4
// baseline (575.765 us; speedup 1.0000x reference)
//
#include <hip/hip_runtime.h>
#include <hip/hip_bf16.h>
#include <math.h>

#define N_NODES  50000
#define N_EDGES  800000
#define FDIM     128
#define N_GRAPHS 500
#define NEG_SLOPE 0.2f
#define EN_TOTAL (N_EDGES + N_NODES)
#define GNPW 8
#define SCAN_NB ((N_NODES + 255) / 256)   // 196

static __device__ __forceinline__ float lrelu(float x) {
    return x >= 0.f ? x : NEG_SLOPE * x;
}

// ---------------- h = X @ W ; asrc = h . a_src ; adst = h . a_dst ----------------
// W in LDS, k-packed transposed: sW4[k4][c] = {W[4k4+0][c],...,W[4k4+3][c]}.
// Lane owns cols {lane, lane+64}; one ds_read_b128 per col per 4 k's (conflict-free,
// consecutive lanes 16B apart). x[k] via wave-uniform s_load. 8 nodes/wave-iter.
// H stored as bf16 (aggregation gathers bf16; attention dots stay fp32).
__global__ __launch_bounds__(256) void gemm_attn(
    const float* __restrict__ X, const float* __restrict__ W,
    const float* __restrict__ Avs, const float* __restrict__ Avd,
    __hip_bfloat16* __restrict__ Hb, float* __restrict__ asrcN, float* __restrict__ adstN)
{
    __shared__ float4 sW4[32 * 128];   // 64 KB
    for (int q = threadIdx.x; q < 4096; q += 256) {
        const int k  = q >> 5;           // W row (32 float4 per row)
        const int c0 = (q & 31) * 4;
        const float4 v = ((const float4*)W)[q];
        float* base = (float*)&sW4[(k >> 2) * 128];
        const int ks = k & 3;
        base[(c0 + 0) * 4 + ks] = v.x;
        base[(c0 + 1) * 4 + ks] = v.y;
        base[(c0 + 2) * 4 + ks] = v.z;
        base[(c0 + 3) * 4 + ks] = v.w;
    }
    __syncthreads();

    const int wv = threadIdx.x >> 6, lane = threadIdx.x & 63;
    const float as_a = Avs[lane], as_b = Avs[lane + 64];
    const float ad_a = Avd[lane], ad_b = Avd[lane + 64];

    const int groups = (N_NODES + GNPW - 1) / GNPW;
    for (int g = blockIdx.x * 4 + wv; g < groups; g += gridDim.x * 4) {
        const int b = __builtin_amdgcn_readfirstlane(g * GNPW);
        const float* xr[GNPW];
        #pragma unroll
        for (int n = 0; n < GNPW; ++n)
            xr[n] = X + (size_t)min(b + n, N_NODES - 1) * FDIM;

        float accA[GNPW], accB[GNPW];
        #pragma unroll
        for (int n = 0; n < GNPW; ++n) { accA[n] = 0.f; accB[n] = 0.f; }

        #pragma unroll 8
        for (int k4 = 0; k4 < 32; ++k4) {
            const float4 wa = sW4[k4 * 128 + lane];
            const float4 wb = sW4[k4 * 128 + lane + 64];
            #pragma unroll
            for (int n = 0; n < GNPW; ++n) {
                const float x0 = xr[n][k4 * 4 + 0];
                const float x1 = xr[n][k4 * 4 + 1];
                const float x2 = xr[n][k4 * 4 + 2];
                const float x3 = xr[n][k4 * 4 + 3];
                accA[n] = fmaf(x3, wa.w, fmaf(x2, wa.z, fmaf(x1, wa.y, fmaf(x0, wa.x, accA[n]))));
                accB[n] = fmaf(x3, wb.w, fmaf(x2, wb.z, fmaf(x1, wb.y, fmaf(x0, wb.x, accB[n]))));
            }
        }

        #pragma unroll
        for (int n = 0; n < GNPW; ++n) {
            const int node = b + n;
            const bool ok = (node < N_NODES);
            if (ok) {
                Hb[(size_t)node * FDIM + lane]      = __float2bfloat16(accA[n]);
                Hb[(size_t)node * FDIM + lane + 64] = __float2bfloat16(accB[n]);
            }
            float ps = accA[n] * as_a + accB[n] * as_b;
            float pd = accA[n] * ad_a + accB[n] * ad_b;
            #pragma unroll
            for (int o = 1; o <= 32; o <<= 1) {
                ps += __shfl_xor(ps, o);
                pd += __shfl_xor(pd, o);
            }
            if (ok && lane == 0) { asrcN[node] = ps; adstN[node] = pd; }
        }
    }
}

// ---------------- CSR build ----------------
__global__ void count_edges(const int* __restrict__ ei, int* __restrict__ cnt) {
    int i = blockIdx.x * 256 + threadIdx.x;
    if (i < EN_TOTAL) {
        int d = (i < N_EDGES) ? ei[N_EDGES + i] : (i - N_EDGES);
        atomicAdd(&cnt[d], 1);
    }
}

__global__ __launch_bounds__(256) void scan_block(const int* __restrict__ cnt,
                                                  int* __restrict__ off,
                                                  int* __restrict__ blockSums) {
    __shared__ int s[256];
    const int i = blockIdx.x * 256 + threadIdx.x;
    s[threadIdx.x] = (i < N_NODES) ? cnt[i] : 0;
    __syncthreads();
    #pragma unroll
    for (int d = 1; d < 256; d <<= 1) {
        int t = (threadIdx.x >= d) ? s[threadIdx.x - d] : 0;
        __syncthreads();
        s[threadIdx.x] += t;
        __syncthreads();
    }
    if (i < N_NODES) off[i + 1] = s[threadIdx.x];
    if (threadIdx.x == 255) blockSums[blockIdx.x] = s[255];
}

__global__ __launch_bounds__(256) void scan_sums(int* __restrict__ blockSums) {
    __shared__ int s[256];
    s[threadIdx.x] = (threadIdx.x < SCAN_NB) ? blockSums[threadIdx.x] : 0;
    __syncthreads();
    #pragma unroll
    for (int d = 1; d < 256; d <<= 1) {
        int t = (threadIdx.x >= d) ? s[threadIdx.x - d] : 0;
        __syncthreads();
        s[threadIdx.x] += t;
        __syncthreads();
    }
    if (threadIdx.x < SCAN_NB)
        blockSums[threadIdx.x] = (threadIdx.x == 0) ? 0 : s[threadIdx.x - 1];
}

__global__ __launch_bounds__(256) void add_base(int* __restrict__ off,
                                                const int* __restrict__ blockSums) {
    const int i = blockIdx.x * 256 + threadIdx.x;
    if (i < N_NODES) off[i + 1] += blockSums[blockIdx.x];
    if (i == 0) off[0] = 0;
}

__global__ void scatter_edges(const int* __restrict__ ei, const int* __restrict__ off,
                              int* __restrict__ cur, int* __restrict__ srcs) {
    int i = blockIdx.x * 256 + threadIdx.x;
    if (i < EN_TOTAL) {
        int s, d;
        if (i < N_EDGES) { s = ei[i]; d = ei[N_EDGES + i]; }
        else             { s = d = i - N_EDGES; }
        int p = off[d] + atomicAdd(&cur[d], 1);
        srcs[p] = s;
    }
}

// ---------------- segment softmax + weighted aggregation (bf16 H gather) ----------------
// One wave per dst node; 8 edge-groups x 8 feature-lanes (16 feats = 32B = 2 x uint4).
__global__ __launch_bounds__(256) void gat_aggregate(
    const __hip_bfloat16* __restrict__ Hb, const int* __restrict__ off,
    const int* __restrict__ srcs,
    const float* __restrict__ asrcN, const float* __restrict__ adstN,
    const float* __restrict__ bias, float* __restrict__ OUT, int doRelu)
{
    const int wave = threadIdx.x >> 6, lane = threadIdx.x & 63;
    const int grp = lane >> 3, fl = lane & 7;

    for (int n = blockIdx.x * 4 + wave; n < N_NODES; n += gridDim.x * 4) {
        const int s0 = off[n], s1 = off[n + 1];
        const int deg = s1 - s0;
        const float ad = adstN[n];

        // pass 1: per-edge logits, lane-parallel; keep first 64 in registers
        float e_reg = -1e30f;
        float m = -1e30f;
        for (int j = s0 + lane; j < s1; j += 64) {
            float e = lrelu(asrcN[srcs[j]] + ad);
            if (j - s0 < 64) e_reg = e;
            m = fmaxf(m, e);
        }
        #pragma unroll
        for (int o = 32; o; o >>= 1) m = fmaxf(m, __shfl_xor(m, o));

        // pass 2: 8 edges in flight; lane owns 16 bf16 features (32B)
        float4 a0 = {0,0,0,0}, a1 = {0,0,0,0}, a2 = {0,0,0,0}, a3 = {0,0,0,0};
        float dn = 0.f;
        const __hip_bfloat16* Hf = Hb + (size_t)fl * 16;
        for (int j = s0 + grp; j < s1; j += 8) {
            const int s = srcs[j];
            const float ex = (deg <= 64)
                ? __expf(__shfl(e_reg, j - s0) - m)
                : __expf(lrelu(asrcN[s] + ad) - m);
            dn += ex;
            const uint4* hp = (const uint4*)(Hf + (size_t)s * FDIM);
            const uint4 u0 = hp[0], u1 = hp[1];
            a0.x += ex * __uint_as_float(u0.x << 16);
            a0.y += ex * __uint_as_float(u0.x & 0xffff0000u);
            a0.z += ex * __uint_as_float(u0.y << 16);
            a0.w += ex * __uint_as_float(u0.y & 0xffff0000u);
            a1.x += ex * __uint_as_float(u0.z << 16);
            a1.y += ex * __uint_as_float(u0.z & 0xffff0000u);
            a1.z += ex * __uint_as_float(u0.w << 16);
            a1.w += ex * __uint_as_float(u0.w & 0xffff0000u);
            a2.x += ex * __uint_as_float(u1.x << 16);
            a2.y += ex * __uint_as_float(u1.x & 0xffff0000u);
            a2.z += ex * __uint_as_float(u1.y << 16);
            a2.w += ex * __uint_as_float(u1.y & 0xffff0000u);
            a3.x += ex * __uint_as_float(u1.z << 16);
            a3.y += ex * __uint_as_float(u1.z & 0xffff0000u);
            a3.z += ex * __uint_as_float(u1.w << 16);
            a3.w += ex * __uint_as_float(u1.w & 0xffff0000u);
        }

        #pragma unroll
        for (int o = 8; o <= 32; o <<= 1) {
            dn  += __shfl_xor(dn, o);
            a0.x += __shfl_xor(a0.x, o); a0.y += __shfl_xor(a0.y, o);
            a0.z += __shfl_xor(a0.z, o); a0.w += __shfl_xor(a0.w, o);
            a1.x += __shfl_xor(a1.x, o); a1.y += __shfl_xor(a1.y, o);
            a1.z += __shfl_xor(a1.z, o); a1.w += __shfl_xor(a1.w, o);
            a2.x += __shfl_xor(a2.x, o); a2.y += __shfl_xor(a2.y, o);
            a2.z += __shfl_xor(a2.z, o); a2.w += __shfl_xor(a2.w, o);
            a3.x += __shfl_xor(a3.x, o); a3.y += __shfl_xor(a3.y, o);
            a3.z += __shfl_xor(a3.z, o); a3.w += __shfl_xor(a3.w, o);
        }

        if (grp == 0) {
            const float rd = 1.f / dn;
            const float4* bp = (const float4*)(bias + fl * 16);
            float4 ov[4] = {a0, a1, a2, a3};
            float4* op = (float4*)(OUT + (size_t)n * FDIM + fl * 16);
            #pragma unroll
            for (int q = 0; q < 4; ++q) {
                float4 b4 = bp[q];
                float4 o4;
                o4.x = ov[q].x * rd + b4.x; o4.y = ov[q].y * rd + b4.y;
                o4.z = ov[q].z * rd + b4.z; o4.w = ov[q].w * rd + b4.w;
                if (doRelu) {
                    o4.x = fmaxf(o4.x, 0.f); o4.y = fmaxf(o4.y, 0.f);
                    o4.z = fmaxf(o4.z, 0.f); o4.w = fmaxf(o4.w, 0.f);
                }
                op[q] = o4;
            }
        }
    }
}

// ---------------- global mean pool (batch sorted) + final linear ----------------
__global__ __launch_bounds__(128) void pool_linear(
    const float* __restrict__ H, const int* __restrict__ batch,
    const float* __restrict__ Wlin, const float* __restrict__ blin,
    float* __restrict__ out)
{
    const int g = blockIdx.x, f = threadIdx.x;
    int a = 0, b = N_NODES;
    while (a < b) { int mid = (a + b) >> 1; if (batch[mid] < g) a = mid + 1; else b = mid; }
    const int lo = a;
    b = N_NODES;
    while (a < b) { int mid = (a + b) >> 1; if (batch[mid] <= g) a = mid + 1; else b = mid; }
    const int hi = a;

    float acc = 0.f;
    for (int n = lo; n < hi; ++n) acc += H[(size_t)n * FDIM + f];
    const float pooled = acc / fmaxf((float)(hi - lo), 1.0f);

    __shared__ float red0[128], red1[128];
    red0[f] = pooled * Wlin[f * 2 + 0];
    red1[f] = pooled * Wlin[f * 2 + 1];
    __syncthreads();
    for (int st = 64; st; st >>= 1) {
        if (f < st) { red0[f] += red0[f + st]; red1[f] += red1[f + st]; }
        __syncthreads();
    }
    if (f == 0) {
        out[g * 2 + 0] = red0[0] + blin[0];
        out[g * 2 + 1] = red1[0] + blin[1];
    }
}

extern "C" void kernel_launch(void* const* d_in, const int* in_sizes, int n_in,
                              void* d_out, int out_size, void* d_ws, size_t ws_size,
                              hipStream_t stream)
{
    const float* x     = (const float*)d_in[0];
    const int*   ei    = (const int*)d_in[1];
    const int*   batch = (const int*)d_in[2];
    const float* W[3]    = {(const float*)d_in[3],  (const float*)d_in[7],  (const float*)d_in[11]};
    const float* avs[3]  = {(const float*)d_in[4],  (const float*)d_in[8],  (const float*)d_in[12]};
    const float* avd[3]  = {(const float*)d_in[5],  (const float*)d_in[9],  (const float*)d_in[13]};
    const float* bias[3] = {(const float*)d_in[6],  (const float*)d_in[10], (const float*)d_in[14]};
    const float* Wlin = (const float*)d_in[15];
    const float* blin = (const float*)d_in[16];
    float* out = (float*)d_out;

    char* w = (char*)d_ws;
    __hip_bfloat16* Hb = (__hip_bfloat16*)w; w += (size_t)N_NODES * FDIM * 2;  // 12.8 MB
    float* hO    = (float*)w; w += (size_t)N_NODES * FDIM * 4;                 // 25.6 MB
    float* attn  = (float*)w; w += 2 * 200192;
    int*   off   = (int*)w;   w += 200192;
    int*   cnt   = (int*)w;   w += 200192;
    int*   bsum  = (int*)w;   w += 4096;
    int*   srcs  = (int*)w;   w += (size_t)EN_TOTAL * 4;
    float* asrcN = attn;
    float* adstN = attn + N_NODES;

    // ---- CSR by destination (topology shared across layers) ----
    hipMemsetAsync(cnt, 0, N_NODES * sizeof(int), stream);
    count_edges<<<(EN_TOTAL + 255) / 256, 256, 0, stream>>>(ei, cnt);
    scan_block<<<SCAN_NB, 256, 0, stream>>>(cnt, off, bsum);
    scan_sums<<<1, 256, 0, stream>>>(bsum);
    add_base<<<SCAN_NB, 256, 0, stream>>>(off, bsum);
    hipMemsetAsync(cnt, 0, N_NODES * sizeof(int), stream);
    scatter_edges<<<(EN_TOTAL + 255) / 256, 256, 0, stream>>>(ei, off, cnt, srcs);

    // ---- 3 GAT layers ----
    const float* hin = x;
    for (int l = 0; l < 3; ++l) {
        gemm_attn<<<512, 256, 0, stream>>>(hin, W[l], avs[l], avd[l], Hb, asrcN, adstN);
        gat_aggregate<<<2048, 256, 0, stream>>>(Hb, off, srcs, asrcN, adstN, bias[l], hO,
                                                (l < 2) ? 1 : 0);
        hin = hO;
    }

    // ---- mean pool + linear ----
    pool_linear<<<N_GRAPHS, 128, 0, stream>>>(hO, batch, Wlin, blin, out);
}